// Round 8
// baseline (84.065 us; speedup 1.0000x reference)
//
#include <hip/hip_runtime.h>
#include <float.h>
#include <math.h>

#define B 128
#define D 128
#define N 3072      // 3*32*32
#define NBUCK 1024  // value buckets (uniform [0,1) -> ~3 elems/bucket)
#define NTHREADS 512
#define NSLICE 96          // column-slice blocks, 32 cols each (96*32 = 3072)
#define SLICE_COLS 32
#define LDS_STRIDE 36      // floats: 144B rows -> float4-aligned, banks spread
#define NPAIR 8256         // 128*129/2 unordered pairs

// ---------------------------------------------------------------------------
// K1 (validated R7): blocks 0..127 bucket-sort x row bid -> xs; blocks
// 128..255 zcos row (bid-128); block 128 zeroes out. Plain stores; kernel
// boundary provides cross-XCD coherence (validated R0/R1/R7).
// ---------------------------------------------------------------------------
__global__ __launch_bounds__(NTHREADS) void prep_kernel(const float* __restrict__ x,
                                                        const float* __restrict__ z,
                                                        float* __restrict__ xs,
                                                        float* __restrict__ zcos,
                                                        float* __restrict__ out) {
    __shared__ unsigned hist[NBUCK];
    __shared__ unsigned bbase[NBUCK];
    __shared__ unsigned wsum[8];
    __shared__ unsigned wpre[8];
    __shared__ float sorted[N];
    __shared__ float inv_s[B];

    int tid = threadIdx.x;
    int bid = blockIdx.x;
    int lane = tid & 63;
    int wid = tid >> 6;

    if (bid < B) {
        // ================= bucket sort of row bid (validated R6/R7) ======
        int row = bid;
        float v[6]; int bb[6];
        const float2* xr = (const float2*)(x + (size_t)row * N);
        #pragma unroll
        for (int k = 0; k < 3; k++) {
            float2 t = xr[tid + k * 512];
            v[2 * k] = t.x; v[2 * k + 1] = t.y;
        }
        #pragma unroll
        for (int k = 0; k < 6; k++) {
            int b = (int)(v[k] * 1024.0f);   // monotone in v
            bb[k] = b < 0 ? 0 : (b > NBUCK - 1 ? NBUCK - 1 : b);
        }
        hist[tid] = 0; hist[tid + 512] = 0;
        __syncthreads();
        #pragma unroll
        for (int k = 0; k < 6; k++) atomicAdd(&hist[bb[k]], 1u);
        __syncthreads();

        // exclusive scan over 1024 bucket counts (2 buckets/thread)
        unsigned c0 = hist[2 * tid], c1 = hist[2 * tid + 1];
        unsigned ps = c0 + c1;                     // pair sum
        #pragma unroll
        for (int o = 1; o < 64; o <<= 1) {         // wave inclusive scan
            unsigned t = __shfl_up(ps, o, 64);
            if (lane >= o) ps += t;
        }
        if (lane == 63) wsum[wid] = ps;
        __syncthreads();
        if (tid == 0) {
            unsigned acc = 0;
            #pragma unroll
            for (int i = 0; i < 8; i++) { wpre[i] = acc; acc += wsum[i]; }
        }
        __syncthreads();
        unsigned excl = ps - (c0 + c1) + wpre[wid];
        bbase[2 * tid] = excl;
        bbase[2 * tid + 1] = excl + c0;
        __syncthreads();

        // scatter (rank via atomicAdd; bbase[b] ends at bucket end)
        #pragma unroll
        for (int k = 0; k < 6; k++) {
            unsigned pos = atomicAdd(&bbase[bb[k]], 1u);
            sorted[pos] = v[k];
        }
        __syncthreads();

        // per-bucket insertion sort (2 buckets/thread, avg ~3 elems each)
        #pragma unroll
        for (int t = 0; t < 2; t++) {
            int b = tid + t * 512;
            int end = (int)bbase[b];
            int st  = end - (int)hist[b];
            for (int i = st + 1; i < end; i++) {
                float key = sorted[i];
                int j2 = i - 1;
                while (j2 >= st && sorted[j2] > key) {
                    sorted[j2 + 1] = sorted[j2];
                    j2--;
                }
                sorted[j2 + 1] = key;
            }
        }
        __syncthreads();

        // coalesced plain stores (kernel boundary provides coherence)
        float4* dst = (float4*)(xs + (size_t)row * N);
        dst[tid] = ((const float4*)sorted)[tid];
        if (tid < 256) dst[tid + 512] = ((const float4*)sorted)[tid + 512];
    } else {
        // ================= zcos row r = bid - 128 (validated) ============
        int r = bid - B;
        if (bid == B && tid == 0) out[0] = 0.f;

        // all-row inverse norms (4 threads per row)
        {
            int r2 = tid >> 2, seg = tid & 3;
            const float4* zr = (const float4*)(z + r2 * D + seg * 32);
            float s = 0.f;
            #pragma unroll
            for (int u = 0; u < 8; u++) {
                float4 vv = zr[u];
                s += vv.x * vv.x + vv.y * vv.y + vv.z * vv.z + vv.w * vv.w;
            }
            s += __shfl_down(s, 2, 4);
            s += __shfl_down(s, 1, 4);
            if (seg == 0) inv_s[r2] = 1.0f / fmaxf(sqrtf(s), 1e-12f);
        }
        __syncthreads();

        // zcos row r: 128 entries, 8 threads/entry, 2 reps (validated shape)
        int e = tid >> 3, sg = tid & 7;
        #pragma unroll
        for (int rep = 0; rep < 2; rep++) {
            int j = e + rep * 64;
            const float4* zi = (const float4*)(z + r * D + sg * 16);
            const float4* zj = (const float4*)(z + j * D + sg * 16);
            float dot = 0.f;
            #pragma unroll
            for (int u = 0; u < 4; u++) {
                float4 a = zi[u], b = zj[u];
                dot += a.x * b.x + a.y * b.y + a.z * b.z + a.w * b.w;
            }
            dot += __shfl_down(dot, 4, 8);
            dot += __shfl_down(dot, 2, 8);
            dot += __shfl_down(dot, 1, 8);
            if (sg == 0) zcos[r * B + j] = dot * inv_s[r] * inv_s[j];
        }
    }
}

// ---------------------------------------------------------------------------
// K2: column-slice EMD partials. Block sb loads all 128 sorted rows x 32 cols
// into LDS once (stride 36: float4-aligned, bank-spread; same-b reads across
// a wave broadcast for free), computes |a-b| partial sums for ALL 8256 pairs
// over its slice. Thread (g,q) caches antipodal a-rows {g, 127-g} in regs
// (triangle balancing: each group does 129 b-iterations) and streams b-rows.
// Global traffic: 1.5 MB read + 3.2 MB partials (vs 100 MB tile-parallel).
// ---------------------------------------------------------------------------
__global__ __launch_bounds__(NTHREADS) void slice_kernel(const float* __restrict__ xs,
                                                         float* __restrict__ part) {
    __shared__ float cols[B * LDS_STRIDE];   // 128 x 36 floats = 18.4 KB
    int tid = threadIdx.x;
    int sb  = blockIdx.x;          // slice 0..95
    int c0  = sb * SLICE_COLS;

    // load 128 rows x 32 cols (1024 float4), 2 float4 per thread, coalesced
    const float4* xs4 = (const float4*)xs;
    #pragma unroll
    for (int t = 0; t < 2; t++) {
        int q = tid + t * 512;               // 0..1023
        int row = q >> 3, k = q & 7;
        float4 v = xs4[row * (N / 4) + (c0 >> 2) + k];
        *(float4*)&cols[row * LDS_STRIDE + 4 * k] = v;
    }
    __syncthreads();

    int g = tid >> 3;              // group 0..63
    int q = tid & 7;
    int a0 = g, a1 = (B - 1) - g;

    // cache both a-rows in registers (8 lanes/group read same addr: broadcast)
    float4 ra[8], rb[8];
    #pragma unroll
    for (int k = 0; k < 8; k++) {
        ra[k] = *(const float4*)&cols[a0 * LDS_STRIDE + 4 * k];
        rb[k] = *(const float4*)&cols[a1 * LDS_STRIDE + 4 * k];
    }

    int base0 = a0 * B - (a0 * (a0 - 1)) / 2 - a0;   // p(a,b) = base + b
    int base1 = a1 * B - (a1 * (a1 - 1)) / 2 - a1;
    float* ps = part + (size_t)sb * NPAIR;

    for (int b = g + q; b < B; b += 8) {
        bool doB = (b >= a1);
        float sA = 0.f, sB = 0.f;
        #pragma unroll
        for (int k = 0; k < 8; k++) {
            float4 lb = *(const float4*)&cols[b * LDS_STRIDE + 4 * k];
            sA += fabsf(ra[k].x - lb.x) + fabsf(ra[k].y - lb.y)
                + fabsf(ra[k].z - lb.z) + fabsf(ra[k].w - lb.w);
            if (doB)
                sB += fabsf(rb[k].x - lb.x) + fabsf(rb[k].y - lb.y)
                    + fabsf(rb[k].z - lb.z) + fabsf(rb[k].w - lb.w);
        }
        ps[base0 + b] = sA;
        if (doB) ps[base1 + b] = sB;
    }
}

// ---------------------------------------------------------------------------
// K3: per-pair reduce over 96 slice partials + MSE vs cosine distance.
// 32 blocks x 512 threads = 16384 = 128x128 (upper triangle active).
// Coalesced: consecutive threads read consecutive pair indices per slice.
// maxv from zcos diagonal (validated R0 pattern).
// ---------------------------------------------------------------------------
__global__ __launch_bounds__(NTHREADS) void reduce_kernel(const float* __restrict__ part,
                                                          const float* __restrict__ zcos,
                                                          float* __restrict__ out) {
    __shared__ float mx[2];
    __shared__ float partial[8];
    int tid = threadIdx.x;
    int gid = blockIdx.x * NTHREADS + tid;
    int lane = tid & 63;
    int w = tid >> 6;

    // diagonal max of zcos (max attained on diagonal — validated R0)
    if (tid < B) {
        float v = zcos[tid * (B + 1)];
        #pragma unroll
        for (int o = 32; o > 0; o >>= 1) v = fmaxf(v, __shfl_down(v, o, 64));
        if ((tid & 63) == 0) mx[tid >> 6] = v;
    }
    __syncthreads();
    float maxv = fmaxf(mx[0], mx[1]);

    int a = gid >> 7, b = gid & (B - 1);
    float acc = 0.f;
    if (b >= a) {
        int p = a * B - (a * (a - 1)) / 2 - a + b;
        float sum = 0.f;
        #pragma unroll 4
        for (int s = 0; s < NSLICE; s++) sum += part[(size_t)s * NPAIR + p];
        float d = sum * (1.0f / N) - (maxv - zcos[a * B + b]);
        float wgt = (a == b) ? 1.0f : 2.0f;   // off-diag counts twice in BxB
        acc = wgt * d * d;
    }
    #pragma unroll
    for (int o = 32; o > 0; o >>= 1) acc += __shfl_down(acc, o, 64);
    if (lane == 0) partial[w] = acc;
    __syncthreads();
    if (tid == 0) {
        float blk = partial[0] + partial[1] + partial[2] + partial[3]
                  + partial[4] + partial[5] + partial[6] + partial[7];
        atomicAdd(out, blk * (1.0f / (B * B)));
    }
}

extern "C" void kernel_launch(void* const* d_in, const int* in_sizes, int n_in,
                              void* d_out, int out_size, void* d_ws, size_t ws_size,
                              hipStream_t stream) {
    const float* z = (const float*)d_in[0];   // [128,128]
    const float* x = (const float*)d_in[1];   // [128,3,32,32]
    float* out = (float*)d_out;               // [1]
    float* ws = (float*)d_ws;

    float* zcos = ws;                         // 16384 floats
    float* xs   = ws + 16384;                 // 393216 floats (sorted rows)
    float* part = ws + 16384 + 393216;        // 96*8256 = 792576 floats

    prep_kernel<<<2 * B, NTHREADS, 0, stream>>>(x, z, xs, zcos, out);
    slice_kernel<<<NSLICE, NTHREADS, 0, stream>>>(xs, part);
    reduce_kernel<<<32, NTHREADS, 0, stream>>>(part, zcos, out);
}

// Round 9
// 74.142 us; speedup vs baseline: 1.1338x; 1.1338x over previous
//
#include <hip/hip_runtime.h>
#include <float.h>
#include <math.h>

#define B 128
#define D 128
#define N 3072      // 3*32*32
#define NBUCK 2048  // value buckets (uniform [0,1) -> ~1.5 elems/bucket)
#define TROW 64     // row-tiles (2 rows each)
#define NTILE (TROW*(TROW+1)/2)   // 2080 upper-tri 2x2 tiles
#define NTHREADS 512

__device__ __forceinline__ void cas_asc(float& a, float& b) {
    float lo = fminf(a, b), hi = fmaxf(a, b);
    a = lo; b = hi;
}

// ---------------------------------------------------------------------------
// K1: blocks 0..127 bucket-sort x row bid -> xs. 2048 buckets; per-bucket
//     sort is an IN-REGISTER bitonic-16 network (independent pipelined LDS
//     loads + compile-time-indexed VALU CAS) instead of R7's dependent
//     scalar-LDS insertion chain (~120cyc/op serialized on worst lane).
//     LDS insertion fallback only if a bucket exceeds 16 (never for this
//     data; correctness guard for arbitrary inputs).
//     Blocks 128..255: zcos row (bid-128) (validated R5/R7 shape);
//     block 128 zeroes out. Plain stores; kernel boundary gives coherence.
// ---------------------------------------------------------------------------
__global__ __launch_bounds__(NTHREADS) void prep_kernel(const float* __restrict__ x,
                                                        const float* __restrict__ z,
                                                        float* __restrict__ xs,
                                                        float* __restrict__ zcos,
                                                        float* __restrict__ out) {
    __shared__ unsigned hist[NBUCK];
    __shared__ unsigned bbase[NBUCK];
    __shared__ unsigned wsum[8];
    __shared__ unsigned wpre[8];
    __shared__ float scat[N];      // scattered (bucket-grouped) elements
    __shared__ float inv_s[B];

    int tid = threadIdx.x;
    int bid = blockIdx.x;
    int lane = tid & 63;
    int wid = tid >> 6;

    if (bid < B) {
        // ================= bucket sort of row bid ========================
        int row = bid;
        float v[6]; int bb[6];
        const float2* xr = (const float2*)(x + (size_t)row * N);
        #pragma unroll
        for (int k = 0; k < 3; k++) {
            float2 t = xr[tid + k * 512];
            v[2 * k] = t.x; v[2 * k + 1] = t.y;
        }
        #pragma unroll
        for (int k = 0; k < 6; k++) {
            int b = (int)(v[k] * (float)NBUCK);   // monotone in v
            bb[k] = b < 0 ? 0 : (b > NBUCK - 1 ? NBUCK - 1 : b);
        }
        #pragma unroll
        for (int k = 0; k < 4; k++) hist[tid + k * 512] = 0;
        __syncthreads();
        #pragma unroll
        for (int k = 0; k < 6; k++) atomicAdd(&hist[bb[k]], 1u);
        __syncthreads();

        // exclusive scan over 2048 bucket counts (4 buckets/thread, contig)
        unsigned c[4];
        unsigned tsum = 0;
        #pragma unroll
        for (int k = 0; k < 4; k++) { c[k] = hist[4 * tid + k]; tsum += c[k]; }
        unsigned ps = tsum;
        #pragma unroll
        for (int o = 1; o < 64; o <<= 1) {         // wave inclusive scan
            unsigned t = __shfl_up(ps, o, 64);
            if (lane >= o) ps += t;
        }
        if (lane == 63) wsum[wid] = ps;
        __syncthreads();
        if (tid == 0) {
            unsigned acc = 0;
            #pragma unroll
            for (int i = 0; i < 8; i++) { wpre[i] = acc; acc += wsum[i]; }
        }
        __syncthreads();
        unsigned excl = ps - tsum + wpre[wid];
        #pragma unroll
        for (int k = 0; k < 4; k++) { bbase[4 * tid + k] = excl; excl += c[k]; }
        __syncthreads();

        // scatter (rank via atomicAdd; bbase[b] ends at bucket end)
        #pragma unroll
        for (int k = 0; k < 6; k++) {
            unsigned pos = atomicAdd(&bbase[bb[k]], 1u);
            scat[pos] = v[k];
        }
        __syncthreads();

        // per-bucket sort: 4 buckets/thread, in-register bitonic-16 network
        #pragma unroll
        for (int t = 0; t < 4; t++) {
            int b = 4 * tid + t;
            int end = (int)bbase[b];
            int m   = (int)hist[b];
            int st  = end - m;
            if (m > 1) {
                if (m <= 16) {
                    float e[16];
                    #pragma unroll
                    for (int i = 0; i < 16; i++)
                        e[i] = (i < m) ? scat[st + i] : FLT_MAX;
                    // bitonic-16 ascending, all indices compile-time
                    #pragma unroll
                    for (int k = 2; k <= 16; k <<= 1) {
                        #pragma unroll
                        for (int j = k >> 1; j >= 1; j >>= 1) {
                            #pragma unroll
                            for (int i = 0; i < 16; i++) {
                                int l = i ^ j;
                                if (l > i) {
                                    if ((i & k) == 0) cas_asc(e[i], e[l]);
                                    else              cas_asc(e[l], e[i]);
                                }
                            }
                        }
                    }
                    #pragma unroll
                    for (int i = 0; i < 16; i++)
                        if (i < m) scat[st + i] = e[i];
                } else {
                    // fallback (never taken for uniform data): LDS insertion
                    for (int i = st + 1; i < end; i++) {
                        float key = scat[i];
                        int j2 = i - 1;
                        while (j2 >= st && scat[j2] > key) {
                            scat[j2 + 1] = scat[j2];
                            j2--;
                        }
                        scat[j2 + 1] = key;
                    }
                }
            }
        }
        __syncthreads();

        // coalesced plain stores (kernel boundary provides coherence)
        float4* dst = (float4*)(xs + (size_t)row * N);
        dst[tid] = ((const float4*)scat)[tid];
        if (tid < 256) dst[tid + 512] = ((const float4*)scat)[tid + 512];
    } else {
        // ================= zcos row r = bid - 128 (validated) ============
        int r = bid - B;
        if (bid == B && tid == 0) out[0] = 0.f;

        // all-row inverse norms (4 threads per row)
        {
            int r2 = tid >> 2, seg = tid & 3;
            const float4* zr = (const float4*)(z + r2 * D + seg * 32);
            float s = 0.f;
            #pragma unroll
            for (int u = 0; u < 8; u++) {
                float4 vv = zr[u];
                s += vv.x * vv.x + vv.y * vv.y + vv.z * vv.z + vv.w * vv.w;
            }
            s += __shfl_down(s, 2, 4);
            s += __shfl_down(s, 1, 4);
            if (seg == 0) inv_s[r2] = 1.0f / fmaxf(sqrtf(s), 1e-12f);
        }
        __syncthreads();

        // zcos row r: 128 entries, 8 threads/entry, 2 reps (validated shape)
        int e = tid >> 3, sg = tid & 7;
        #pragma unroll
        for (int rep = 0; rep < 2; rep++) {
            int j = e + rep * 64;
            const float4* zi = (const float4*)(z + r * D + sg * 16);
            const float4* zj = (const float4*)(z + j * D + sg * 16);
            float dot = 0.f;
            #pragma unroll
            for (int u = 0; u < 4; u++) {
                float4 a = zi[u], b = zj[u];
                dot += a.x * b.x + a.y * b.y + a.z * b.z + a.w * b.w;
            }
            dot += __shfl_down(dot, 4, 8);
            dot += __shfl_down(dot, 2, 8);
            dot += __shfl_down(dot, 1, 8);
            if (sg == 0) zcos[r * B + j] = dot * inv_s[r] * inv_s[j];
        }
    }
}

// ---------------------------------------------------------------------------
// K2: pair tiles (validated R0/R7 math/decode). 256 blocks x 8 waves; maxv
// from zcos diagonal; 2048 primary tiles + 32 leftovers spread across 32
// different blocks; one atomicAdd per block.
// ---------------------------------------------------------------------------
__global__ __launch_bounds__(NTHREADS) void pair_kernel(const float* __restrict__ xs,
                                                        const float* __restrict__ zcos,
                                                        float* __restrict__ out) {
    __shared__ float mx[2];
    __shared__ float partial[8];
    int tid = threadIdx.x;
    int bid = blockIdx.x;
    int lane = tid & 63;
    int w = tid >> 6;

    // diagonal max of zcos (max attained on diagonal — validated R0)
    if (tid < B) {
        float v = zcos[tid * (B + 1)];
        #pragma unroll
        for (int o = 32; o > 0; o >>= 1) v = fmaxf(v, __shfl_down(v, o, 64));
        if ((tid & 63) == 0) mx[tid >> 6] = v;
    }
    __syncthreads();
    float maxv = fmaxf(mx[0], mx[1]);

    float acc = 0.f;
    int nT = (w == 0 && (bid & 7) == 0) ? 2 : 1;
    for (int pass = 0; pass < nT; ++pass) {
        int T = (pass == 0) ? (bid * 8 + w) : (2048 + (bid >> 3));

        // decode T -> (ti, tj), ti<=tj over TROW=64 (validated decode)
        float ff = (float)(2 * TROW + 1);
        int ti = (int)((ff - sqrtf(ff * ff - 8.0f * (float)T)) * 0.5f);
        if (ti < 0) ti = 0;
        if (ti > TROW - 1) ti = TROW - 1;
        while ((ti + 1) * TROW - ((ti + 1) * ti) / 2 <= T) ti++;
        while (ti * TROW - (ti * (ti - 1)) / 2 > T) ti--;
        int tj = ti + (T - (ti * TROW - (ti * (ti - 1)) / 2));

        int r0 = 2 * ti, r1 = r0 + 1;
        int c0 = 2 * tj, c1 = c0 + 1;

        const float4* a0 = (const float4*)(xs + (size_t)r0 * N);
        const float4* a1 = (const float4*)(xs + (size_t)r1 * N);
        const float4* b0 = (const float4*)(xs + (size_t)c0 * N);
        const float4* b1 = (const float4*)(xs + (size_t)c1 * N);

        float s00 = 0.f, s01 = 0.f, s10 = 0.f, s11 = 0.f;
        #pragma unroll
        for (int u = 0; u < N / 4 / 64; u++) {          // 12 iterations
            int idx = lane + u * 64;
            float4 va0 = a0[idx], va1 = a1[idx];
            float4 vb0 = b0[idx], vb1 = b1[idx];
            s00 += fabsf(va0.x - vb0.x) + fabsf(va0.y - vb0.y)
                 + fabsf(va0.z - vb0.z) + fabsf(va0.w - vb0.w);
            s01 += fabsf(va0.x - vb1.x) + fabsf(va0.y - vb1.y)
                 + fabsf(va0.z - vb1.z) + fabsf(va0.w - vb1.w);
            s10 += fabsf(va1.x - vb0.x) + fabsf(va1.y - vb0.y)
                 + fabsf(va1.z - vb0.z) + fabsf(va1.w - vb0.w);
            s11 += fabsf(va1.x - vb1.x) + fabsf(va1.y - vb1.y)
                 + fabsf(va1.z - vb1.z) + fabsf(va1.w - vb1.w);
        }
        #pragma unroll
        for (int o = 32; o > 0; o >>= 1) {
            s00 += __shfl_down(s00, o, 64);
            s01 += __shfl_down(s01, o, 64);
            s10 += __shfl_down(s10, o, 64);
            s11 += __shfl_down(s11, o, 64);
        }
        if (lane == 0) {
            bool diag = (ti == tj);
            float w00 = diag ? 1.0f : 2.0f;
            float w01 = 2.0f;
            float w10 = diag ? 0.0f : 2.0f;
            float w11 = diag ? 1.0f : 2.0f;
            float inv_n = 1.0f / N;
            float d00 = s00 * inv_n - (maxv - zcos[r0 * B + c0]);
            float d01 = s01 * inv_n - (maxv - zcos[r0 * B + c1]);
            float d10 = s10 * inv_n - (maxv - zcos[r1 * B + c0]);
            float d11 = s11 * inv_n - (maxv - zcos[r1 * B + c1]);
            acc += w00 * d00 * d00 + w01 * d01 * d01
                 + w10 * d10 * d10 + w11 * d11 * d11;
        }
    }
    if (lane == 0) partial[w] = acc;
    __syncthreads();
    if (tid == 0) {
        float blk = partial[0] + partial[1] + partial[2] + partial[3]
                  + partial[4] + partial[5] + partial[6] + partial[7];
        atomicAdd(out, blk * (1.0f / (B * B)));
    }
}

extern "C" void kernel_launch(void* const* d_in, const int* in_sizes, int n_in,
                              void* d_out, int out_size, void* d_ws, size_t ws_size,
                              hipStream_t stream) {
    const float* z = (const float*)d_in[0];   // [128,128]
    const float* x = (const float*)d_in[1];   // [128,3,32,32]
    float* out = (float*)d_out;               // [1]
    float* ws = (float*)d_ws;

    float* zcos = ws;                         // 16384 floats
    float* xs   = ws + 16384;                 // 393216 floats (sorted rows)

    prep_kernel<<<2 * B, NTHREADS, 0, stream>>>(x, z, xs, zcos, out);
    pair_kernel<<<2 * B, NTHREADS, 0, stream>>>(xs, zcos, out);
}

// Round 10
// 71.462 us; speedup vs baseline: 1.1764x; 1.0375x over previous
//
#include <hip/hip_runtime.h>
#include <float.h>
#include <math.h>

#define B 128
#define D 128
#define N 3072      // 3*32*32
#define NBUCK 2048  // value buckets (uniform [0,1) -> ~1.5 elems/bucket)
#define TROW 64     // row-tiles (2 rows each)
#define NTILE (TROW*(TROW+1)/2)   // 2080 upper-tri 2x2 tiles
#define NTHREADS 512

__device__ __forceinline__ void cas_asc(float& a, float& b) {
    float lo = fminf(a, b), hi = fmaxf(a, b);
    a = lo; b = hi;
}

// ---------------------------------------------------------------------------
// K1: blocks 0..127 bucket-sort x row bid -> xs (validated R9 pipeline).
//     Changes vs R9: outer bucket loop is NOT unrolled (one register array
//     live at a time -> no VGPR spill), and buckets with m<=8 use a
//     bitonic-8 network (24 CAS) instead of bitonic-16 (80 CAS); m<=16
//     bitonic-16 and the (never-taken) LDS insertion fallback guard
//     arbitrary data. Blocks 128..255: zcos row (validated); block 128
//     zeroes out. Plain stores; kernel boundary gives coherence.
// ---------------------------------------------------------------------------
__global__ __launch_bounds__(NTHREADS) void prep_kernel(const float* __restrict__ x,
                                                        const float* __restrict__ z,
                                                        float* __restrict__ xs,
                                                        float* __restrict__ zcos,
                                                        float* __restrict__ out) {
    __shared__ unsigned hist[NBUCK];
    __shared__ unsigned bbase[NBUCK];
    __shared__ unsigned wsum[8];
    __shared__ unsigned wpre[8];
    __shared__ float scat[N];      // scattered (bucket-grouped) elements
    __shared__ float inv_s[B];

    int tid = threadIdx.x;
    int bid = blockIdx.x;
    int lane = tid & 63;
    int wid = tid >> 6;

    if (bid < B) {
        // ================= bucket sort of row bid ========================
        int row = bid;
        float v[6]; int bb[6];
        const float2* xr = (const float2*)(x + (size_t)row * N);
        #pragma unroll
        for (int k = 0; k < 3; k++) {
            float2 t = xr[tid + k * 512];
            v[2 * k] = t.x; v[2 * k + 1] = t.y;
        }
        #pragma unroll
        for (int k = 0; k < 6; k++) {
            int b = (int)(v[k] * (float)NBUCK);   // monotone in v
            bb[k] = b < 0 ? 0 : (b > NBUCK - 1 ? NBUCK - 1 : b);
        }
        #pragma unroll
        for (int k = 0; k < 4; k++) hist[tid + k * 512] = 0;
        __syncthreads();
        #pragma unroll
        for (int k = 0; k < 6; k++) atomicAdd(&hist[bb[k]], 1u);
        __syncthreads();

        // exclusive scan over 2048 bucket counts (4 buckets/thread, contig)
        unsigned c[4];
        unsigned tsum = 0;
        #pragma unroll
        for (int k = 0; k < 4; k++) { c[k] = hist[4 * tid + k]; tsum += c[k]; }
        unsigned ps = tsum;
        #pragma unroll
        for (int o = 1; o < 64; o <<= 1) {         // wave inclusive scan
            unsigned t = __shfl_up(ps, o, 64);
            if (lane >= o) ps += t;
        }
        if (lane == 63) wsum[wid] = ps;
        __syncthreads();
        if (tid == 0) {
            unsigned acc = 0;
            #pragma unroll
            for (int i = 0; i < 8; i++) { wpre[i] = acc; acc += wsum[i]; }
        }
        __syncthreads();
        unsigned excl = ps - tsum + wpre[wid];
        #pragma unroll
        for (int k = 0; k < 4; k++) { bbase[4 * tid + k] = excl; excl += c[k]; }
        __syncthreads();

        // scatter (rank via atomicAdd; bbase[b] ends at bucket end)
        #pragma unroll
        for (int k = 0; k < 6; k++) {
            unsigned pos = atomicAdd(&bbase[bb[k]], 1u);
            scat[pos] = v[k];
        }
        __syncthreads();

        // per-bucket sort: 4 buckets/thread, ONE at a time (no unroll ->
        // single live register array, no spill)
        #pragma unroll 1
        for (int t = 0; t < 4; t++) {
            int b = 4 * tid + t;
            int end = (int)bbase[b];
            int m   = (int)hist[b];
            int st  = end - m;
            if (m > 1) {
                if (m <= 8) {
                    float e[8];
                    #pragma unroll
                    for (int i = 0; i < 8; i++)
                        e[i] = (i < m) ? scat[st + i] : FLT_MAX;
                    #pragma unroll
                    for (int k = 2; k <= 8; k <<= 1) {
                        #pragma unroll
                        for (int j = k >> 1; j >= 1; j >>= 1) {
                            #pragma unroll
                            for (int i = 0; i < 8; i++) {
                                int l = i ^ j;
                                if (l > i) {
                                    if ((i & k) == 0) cas_asc(e[i], e[l]);
                                    else              cas_asc(e[l], e[i]);
                                }
                            }
                        }
                    }
                    #pragma unroll
                    for (int i = 0; i < 8; i++)
                        if (i < m) scat[st + i] = e[i];
                } else if (m <= 16) {
                    float e[16];
                    #pragma unroll
                    for (int i = 0; i < 16; i++)
                        e[i] = (i < m) ? scat[st + i] : FLT_MAX;
                    #pragma unroll
                    for (int k = 2; k <= 16; k <<= 1) {
                        #pragma unroll
                        for (int j = k >> 1; j >= 1; j >>= 1) {
                            #pragma unroll
                            for (int i = 0; i < 16; i++) {
                                int l = i ^ j;
                                if (l > i) {
                                    if ((i & k) == 0) cas_asc(e[i], e[l]);
                                    else              cas_asc(e[l], e[i]);
                                }
                            }
                        }
                    }
                    #pragma unroll
                    for (int i = 0; i < 16; i++)
                        if (i < m) scat[st + i] = e[i];
                } else {
                    // fallback (never taken for uniform data): LDS insertion
                    for (int i = st + 1; i < end; i++) {
                        float key = scat[i];
                        int j2 = i - 1;
                        while (j2 >= st && scat[j2] > key) {
                            scat[j2 + 1] = scat[j2];
                            j2--;
                        }
                        scat[j2 + 1] = key;
                    }
                }
            }
        }
        __syncthreads();

        // coalesced plain stores (kernel boundary provides coherence)
        float4* dst = (float4*)(xs + (size_t)row * N);
        dst[tid] = ((const float4*)scat)[tid];
        if (tid < 256) dst[tid + 512] = ((const float4*)scat)[tid + 512];
    } else {
        // ================= zcos row r = bid - 128 (validated) ============
        int r = bid - B;
        if (bid == B && tid == 0) out[0] = 0.f;

        // all-row inverse norms (4 threads per row)
        {
            int r2 = tid >> 2, seg = tid & 3;
            const float4* zr = (const float4*)(z + r2 * D + seg * 32);
            float s = 0.f;
            #pragma unroll
            for (int u = 0; u < 8; u++) {
                float4 vv = zr[u];
                s += vv.x * vv.x + vv.y * vv.y + vv.z * vv.z + vv.w * vv.w;
            }
            s += __shfl_down(s, 2, 4);
            s += __shfl_down(s, 1, 4);
            if (seg == 0) inv_s[r2] = 1.0f / fmaxf(sqrtf(s), 1e-12f);
        }
        __syncthreads();

        // zcos row r: 128 entries, 8 threads/entry, 2 reps (validated shape)
        int e = tid >> 3, sg = tid & 7;
        #pragma unroll
        for (int rep = 0; rep < 2; rep++) {
            int j = e + rep * 64;
            const float4* zi = (const float4*)(z + r * D + sg * 16);
            const float4* zj = (const float4*)(z + j * D + sg * 16);
            float dot = 0.f;
            #pragma unroll
            for (int u = 0; u < 4; u++) {
                float4 a = zi[u], b = zj[u];
                dot += a.x * b.x + a.y * b.y + a.z * b.z + a.w * b.w;
            }
            dot += __shfl_down(dot, 4, 8);
            dot += __shfl_down(dot, 2, 8);
            dot += __shfl_down(dot, 1, 8);
            if (sg == 0) zcos[r * B + j] = dot * inv_s[r] * inv_s[j];
        }
    }
}

// ---------------------------------------------------------------------------
// K2: pair tiles (validated R0/R7 math/decode) with bijective XCD swizzle:
// swz = (bid&7)*32 + (bid>>3) gives each XCD a contiguous tile range ->
// contiguous ti rows -> narrower per-XCD row working set (fewer L3 pulls).
// Leftovers: 32 blocks with (swz&7)==0, q = swz>>3 in [0,32) bijective.
// ---------------------------------------------------------------------------
__global__ __launch_bounds__(NTHREADS) void pair_kernel(const float* __restrict__ xs,
                                                        const float* __restrict__ zcos,
                                                        float* __restrict__ out) {
    __shared__ float mx[2];
    __shared__ float partial[8];
    int tid = threadIdx.x;
    int bid = blockIdx.x;
    int lane = tid & 63;
    int w = tid >> 6;
    int swz = ((bid & 7) << 5) | (bid >> 3);   // bijective on [0,256)

    // diagonal max of zcos (max attained on diagonal — validated R0)
    if (tid < B) {
        float v = zcos[tid * (B + 1)];
        #pragma unroll
        for (int o = 32; o > 0; o >>= 1) v = fmaxf(v, __shfl_down(v, o, 64));
        if ((tid & 63) == 0) mx[tid >> 6] = v;
    }
    __syncthreads();
    float maxv = fmaxf(mx[0], mx[1]);

    float acc = 0.f;
    int nT = (w == 0 && (swz & 7) == 0) ? 2 : 1;
    for (int pass = 0; pass < nT; ++pass) {
        int T = (pass == 0) ? (swz * 8 + w) : (2048 + (swz >> 3));

        // decode T -> (ti, tj), ti<=tj over TROW=64 (validated decode)
        float ff = (float)(2 * TROW + 1);
        int ti = (int)((ff - sqrtf(ff * ff - 8.0f * (float)T)) * 0.5f);
        if (ti < 0) ti = 0;
        if (ti > TROW - 1) ti = TROW - 1;
        while ((ti + 1) * TROW - ((ti + 1) * ti) / 2 <= T) ti++;
        while (ti * TROW - (ti * (ti - 1)) / 2 > T) ti--;
        int tj = ti + (T - (ti * TROW - (ti * (ti - 1)) / 2));

        int r0 = 2 * ti, r1 = r0 + 1;
        int c0 = 2 * tj, c1 = c0 + 1;

        const float4* a0 = (const float4*)(xs + (size_t)r0 * N);
        const float4* a1 = (const float4*)(xs + (size_t)r1 * N);
        const float4* b0 = (const float4*)(xs + (size_t)c0 * N);
        const float4* b1 = (const float4*)(xs + (size_t)c1 * N);

        float s00 = 0.f, s01 = 0.f, s10 = 0.f, s11 = 0.f;
        #pragma unroll
        for (int u = 0; u < N / 4 / 64; u++) {          // 12 iterations
            int idx = lane + u * 64;
            float4 va0 = a0[idx], va1 = a1[idx];
            float4 vb0 = b0[idx], vb1 = b1[idx];
            s00 += fabsf(va0.x - vb0.x) + fabsf(va0.y - vb0.y)
                 + fabsf(va0.z - vb0.z) + fabsf(va0.w - vb0.w);
            s01 += fabsf(va0.x - vb1.x) + fabsf(va0.y - vb1.y)
                 + fabsf(va0.z - vb1.z) + fabsf(va0.w - vb1.w);
            s10 += fabsf(va1.x - vb0.x) + fabsf(va1.y - vb0.y)
                 + fabsf(va1.z - vb0.z) + fabsf(va1.w - vb0.w);
            s11 += fabsf(va1.x - vb1.x) + fabsf(va1.y - vb1.y)
                 + fabsf(va1.z - vb1.z) + fabsf(va1.w - vb1.w);
        }
        #pragma unroll
        for (int o = 32; o > 0; o >>= 1) {
            s00 += __shfl_down(s00, o, 64);
            s01 += __shfl_down(s01, o, 64);
            s10 += __shfl_down(s10, o, 64);
            s11 += __shfl_down(s11, o, 64);
        }
        if (lane == 0) {
            bool diag = (ti == tj);
            float w00 = diag ? 1.0f : 2.0f;
            float w01 = 2.0f;
            float w10 = diag ? 0.0f : 2.0f;
            float w11 = diag ? 1.0f : 2.0f;
            float inv_n = 1.0f / N;
            float d00 = s00 * inv_n - (maxv - zcos[r0 * B + c0]);
            float d01 = s01 * inv_n - (maxv - zcos[r0 * B + c1]);
            float d10 = s10 * inv_n - (maxv - zcos[r1 * B + c0]);
            float d11 = s11 * inv_n - (maxv - zcos[r1 * B + c1]);
            acc += w00 * d00 * d00 + w01 * d01 * d01
                 + w10 * d10 * d10 + w11 * d11 * d11;
        }
    }
    if (lane == 0) partial[w] = acc;
    __syncthreads();
    if (tid == 0) {
        float blk = partial[0] + partial[1] + partial[2] + partial[3]
                  + partial[4] + partial[5] + partial[6] + partial[7];
        atomicAdd(out, blk * (1.0f / (B * B)));
    }
}

extern "C" void kernel_launch(void* const* d_in, const int* in_sizes, int n_in,
                              void* d_out, int out_size, void* d_ws, size_t ws_size,
                              hipStream_t stream) {
    const float* z = (const float*)d_in[0];   // [128,128]
    const float* x = (const float*)d_in[1];   // [128,3,32,32]
    float* out = (float*)d_out;               // [1]
    float* ws = (float*)d_ws;

    float* zcos = ws;                         // 16384 floats
    float* xs   = ws + 16384;                 // 393216 floats (sorted rows)

    prep_kernel<<<2 * B, NTHREADS, 0, stream>>>(x, z, xs, zcos, out);
    pair_kernel<<<2 * B, NTHREADS, 0, stream>>>(xs, zcos, out);
}